// Round 1
// baseline (1804.794 us; speedup 1.0000x reference)
//
#include <hip/hip_runtime.h>
#include <math.h>

#define BATCH 8192
#define M 200
#define E 64
#define OTHER_D 128
#define FEA 256
#define H1 96    // ADIM/2
#define F1 128   // FEA/2
#define F2 85    // FEA/3
#define F3 64    // FEA/4

// ---------------------------------------------------------------------------
// Kernel 1: per-batch attention.
// a = [hist, hist*tgt, tgt];  h = relu(a@aW1 + ab1);  aij = h@aW2 + ab2
// tmp[b,k] = sum_m aij[b,m] * hist[b,m,k]
// Folded: h = relu(hist_b @ (W1a + diag(tgt)W1b) + (tgt@W1c + ab1))
// ---------------------------------------------------------------------------
__global__ __launch_bounds__(256) void attn_kernel(
    const float* __restrict__ hist,    // B*M*E
    const float* __restrict__ target,  // B*E
    const float* __restrict__ aW1,     // 192*96 row-major
    const float* __restrict__ ab1,     // 96
    const float* __restrict__ aW2,     // 96
    const float* __restrict__ ab2,     // 1
    float* __restrict__ tmp_out)       // B*E
{
    __shared__ float tgtS[E];
    __shared__ float Wb[E * H1];        // 6144 floats = 24 KB, row k stride 96
    __shared__ float beS[H1];
    __shared__ float aW2S[H1];
    __shared__ float histS[M * 65];     // padded rows: bank-conflict-free
    __shared__ float aijS[M];
    __shared__ float partS[4 * E];

    const int t = threadIdx.x;
    const int b = blockIdx.x;

    if (t < E) tgtS[t] = target[(size_t)b * E + t];
    __syncthreads();

    // Effective weight: Wb[k*96+j] = aW1[k*96+j] + tgt[k]*aW1[(64+k)*96+j]
    for (int idx = t; idx < E * H1; idx += 256) {
        int k = idx / H1;
        Wb[idx] = aW1[idx] + tgtS[k] * aW1[E * H1 + idx];
    }
    // Effective bias: be[j] = ab1[j] + sum_k tgt[k]*aW1[(128+k)*96+j]
    if (t < H1) {
        float s = ab1[t];
        for (int k = 0; k < E; ++k)
            s += tgtS[k] * aW1[(2 * E + k) * H1 + t];
        beS[t] = s;
        aW2S[t] = aW2[t];
    }
    // Stage hist_b (coalesced global dwords -> padded LDS rows)
    const float* hb = hist + (size_t)b * (M * E);
    for (int idx = t; idx < M * E; idx += 256) {
        int m = idx >> 6, k = idx & 63;
        histS[m * 65 + k] = hb[idx];
    }
    __syncthreads();

    // Main compute: thread t handles row m = t (t < 200)
    if (t < M) {
        float hreg[E];
        #pragma unroll
        for (int k = 0; k < E; ++k) hreg[k] = histS[t * 65 + k];

        float a2 = ab2[0];
        for (int j0 = 0; j0 < H1; j0 += 8) {   // 12 j-tiles
            float acc[8];
            #pragma unroll
            for (int i = 0; i < 8; ++i) acc[i] = beS[j0 + i];
            #pragma unroll
            for (int k = 0; k < E; ++k) {      // unrolled so hreg stays in VGPRs
                const float hk = hreg[k];
                #pragma unroll
                for (int i = 0; i < 8; ++i)
                    acc[i] += hk * Wb[k * H1 + j0 + i];  // wave-uniform broadcast
            }
            #pragma unroll
            for (int i = 0; i < 8; ++i) {
                float h = acc[i] > 0.f ? acc[i] : 0.f;
                a2 += h * aW2S[j0 + i];
            }
        }
        aijS[t] = a2;
    }
    __syncthreads();

    // tmp[k] = sum_m aij[m]*hist[m,k]; 4 partial groups of 50 rows
    {
        int k = t & 63, g = t >> 6;
        float s = 0.f;
        for (int m = g * 50; m < g * 50 + 50; ++m)
            s += aijS[m] * histS[m * 65 + k];
        partS[g * E + k] = s;
    }
    __syncthreads();
    if (t < E) {
        float s = partS[t] + partS[E + t] + partS[2 * E + t] + partS[3 * E + t];
        tmp_out[(size_t)b * E + t] = s;
    }
}

// ---------------------------------------------------------------------------
// Kernel 2: MLP head. x=[tmp|target|other] (256) -> 128 -> 85 -> 64 -> sigmoid
// 16 rows per block of 256 threads.
// ---------------------------------------------------------------------------
__global__ __launch_bounds__(256) void mlp_kernel(
    const float* __restrict__ tmp,     // B*64
    const float* __restrict__ target,  // B*64
    const float* __restrict__ other,   // B*128
    const float* __restrict__ oW1, const float* __restrict__ ob1,  // 256x128
    const float* __restrict__ oW2, const float* __restrict__ ob2,  // 128x85
    const float* __restrict__ oW3, const float* __restrict__ ob3,  // 85x64
    const float* __restrict__ fW,  const float* __restrict__ fb,   // 64
    float* __restrict__ out)           // B
{
    const int t = threadIdx.x;
    const int R0 = blockIdx.x * 16;
    __shared__ float xS[16 * 256];
    __shared__ float h1S[16 * 128];
    __shared__ float h2S[16 * 85];
    __shared__ float h3S[16 * 64];

    for (int idx = t; idx < 16 * 256; idx += 256) {
        int r = idx >> 8, c = idx & 255;
        int R = R0 + r;
        float v;
        if (c < 64)       v = tmp[(size_t)R * 64 + c];
        else if (c < 128) v = target[(size_t)R * 64 + (c - 64)];
        else              v = other[(size_t)R * 128 + (c - 128)];
        xS[idx] = v;
    }
    __syncthreads();

    // Layer 1: 16x128 outputs; thread owns fixed j = t&127, 8 rows
    {
        int j = t & 127, hi = t >> 7;
        float acc[8];
        #pragma unroll
        for (int i = 0; i < 8; ++i) acc[i] = ob1[j];
        for (int c = 0; c < FEA; ++c) {
            float w = oW1[c * F1 + j];           // coalesced, L2-hot
            #pragma unroll
            for (int i = 0; i < 8; ++i)
                acc[i] += xS[(2 * i + hi) * 256 + c] * w;  // broadcast
        }
        #pragma unroll
        for (int i = 0; i < 8; ++i)
            h1S[(2 * i + hi) * F1 + j] = fmaxf(acc[i], 0.f);
    }
    __syncthreads();

    // Layer 2: 16x85
    for (int oidx = t; oidx < 16 * F2; oidx += 256) {
        int r = oidx / F2, j = oidx % F2;
        float s = ob2[j];
        for (int c = 0; c < F1; ++c)
            s += h1S[r * F1 + c] * oW2[c * F2 + j];
        h2S[oidx] = fmaxf(s, 0.f);
    }
    __syncthreads();

    // Layer 3: 16x64
    for (int oidx = t; oidx < 16 * F3; oidx += 256) {
        int r = oidx >> 6, j = oidx & 63;
        float s = ob3[j];
        for (int c = 0; c < F2; ++c)
            s += h2S[r * F2 + c] * oW3[c * F3 + j];
        h3S[oidx] = fmaxf(s, 0.f);
    }
    __syncthreads();

    // Final: 16 outputs
    if (t < 16) {
        float s = fb[0];
        for (int c = 0; c < F3; ++c)
            s += h3S[t * F3 + c] * fW[c];
        out[R0 + t] = 1.f / (1.f + __expf(-s));
    }
}

extern "C" void kernel_launch(void* const* d_in, const int* in_sizes, int n_in,
                              void* d_out, int out_size, void* d_ws, size_t ws_size,
                              hipStream_t stream) {
    const float* hist   = (const float*)d_in[0];
    const float* target = (const float*)d_in[1];
    const float* other  = (const float*)d_in[2];
    const float* aW1    = (const float*)d_in[3];
    const float* ab1    = (const float*)d_in[4];
    const float* aW2    = (const float*)d_in[5];
    const float* ab2    = (const float*)d_in[6];
    const float* oW1    = (const float*)d_in[7];
    const float* ob1    = (const float*)d_in[8];
    const float* oW2    = (const float*)d_in[9];
    const float* ob2    = (const float*)d_in[10];
    const float* oW3    = (const float*)d_in[11];
    const float* ob3    = (const float*)d_in[12];
    const float* fW     = (const float*)d_in[13];
    const float* fb     = (const float*)d_in[14];
    float* out = (float*)d_out;
    float* tmp = (float*)d_ws;   // B*64 fp32 = 2 MB scratch

    attn_kernel<<<BATCH, 256, 0, stream>>>(hist, target, aW1, ab1, aW2, ab2, tmp);
    mlp_kernel<<<BATCH / 16, 256, 0, stream>>>(tmp, target, other,
                                               oW1, ob1, oW2, ob2, oW3, ob3,
                                               fW, fb, out);
}

// Round 2
// 824.160 us; speedup vs baseline: 2.1899x; 2.1899x over previous
//
#include <hip/hip_runtime.h>
#include <math.h>

#define BATCH 8192
#define M 200
#define E 64
#define H1 96    // ADIM/2
#define F1 128   // FEA/2
#define F2 85    // FEA/3
#define F3 64    // FEA/4
#define SH 72    // padded LDS row stride in halfs (144 B, 16B-aligned, non-pow2)
#define MT 13    // ceil(200/16) m-tiles (rows 200..207 zero-padded)

typedef _Float16 half8_t __attribute__((ext_vector_type(8)));
typedef _Float16 half4_t __attribute__((ext_vector_type(4)));
typedef float floatx4 __attribute__((ext_vector_type(4)));

// One block per batch row b. Phases:
//  A) stage: tgt, fold Wb=aW1a+diag(tgt)aW1b -> WbT (fp16, k-contiguous),
//     be = ab1 + tgt@aW1c, hist_b -> LDS fp16 (rows padded to 208, zeroed)
//  B) MFMA: C(200x96) = H @ Wb via 16x16x32 f16; epilogue fuses
//     relu(C+be)@aW2 -> aij[m] with in-quad shuffle reduction
//  C) tmp[k] = sum_m aij[m]*H[m][k]
//  D) fused MLP head 256->128->85->64->sigmoid, weights from global (L2-hot)
__global__ __launch_bounds__(256, 3) void din_kernel(
    const float* __restrict__ hist, const float* __restrict__ target,
    const float* __restrict__ other,
    const float* __restrict__ aW1, const float* __restrict__ ab1,
    const float* __restrict__ aW2, const float* __restrict__ ab2,
    const float* __restrict__ oW1, const float* __restrict__ ob1,
    const float* __restrict__ oW2, const float* __restrict__ ob2,
    const float* __restrict__ oW3, const float* __restrict__ ob3,
    const float* __restrict__ fW,  const float* __restrict__ fb,
    float* __restrict__ out)
{
    __shared__ _Float16 histS[208 * SH];   // 29952 B
    __shared__ _Float16 WbT[H1 * SH];      // 13824 B, row j: k-contiguous
    __shared__ float tgtS[E];
    __shared__ float beS[H1];
    __shared__ float aW2S[H1];
    __shared__ float aijS[208];
    __shared__ float partS[4 * E];
    __shared__ float xS[256];
    __shared__ float h1p[256];
    __shared__ float h1S[F1];
    __shared__ float h2p[256];
    __shared__ float h2S[F2];
    __shared__ float h3S[F3];
    __shared__ float ab2S;

    const int t = threadIdx.x;
    const int b = blockIdx.x;

    if (t < E) tgtS[t] = target[(size_t)b * E + t];
    if (t == 0) ab2S = ab2[0];
    __syncthreads();

    // ---- Phase A: folds + staging -------------------------------------
    // WbT[j][k] = aW1[k][j] + tgt[k]*aW1[64+k][j]   (fp16, transposed)
    for (int idx = t; idx < E * H1; idx += 256) {
        int k = idx / H1, j = idx - k * H1;
        float w = aW1[idx] + tgtS[k] * aW1[E * H1 + idx];
        WbT[j * SH + k] = (_Float16)w;
    }
    // be[j] = ab1[j] + sum_k tgt[k]*aW1[128+k][j]
    if (t < H1) {
        float s = ab1[t];
        for (int k = 0; k < E; ++k)
            s += tgtS[k] * aW1[(2 * E + k) * H1 + t];
        beS[t] = s;
        aW2S[t] = aW2[t];
    }
    // hist row b -> LDS fp16 (float4 global loads, half4 LDS stores)
    {
        const float4* hb4 = (const float4*)(hist + (size_t)b * (M * E));
        for (int i = t; i < (M * E) / 4; i += 256) {   // 3200 vec4
            float4 v = hb4[i];
            int m = i >> 4, c4 = (i & 15) * 4;
            half4_t hv = { (_Float16)v.x, (_Float16)v.y,
                           (_Float16)v.z, (_Float16)v.w };
            *(half4_t*)&histS[m * SH + c4] = hv;
        }
        // zero pad rows 200..207 (k<64 only — MFMA A-frags read them)
        for (int i = t; i < 8 * 64; i += 256)
            histS[(200 + (i >> 6)) * SH + (i & 63)] = (_Float16)0.f;
    }
    __syncthreads();

    // ---- Phase B: MFMA C = H @ Wb, fused aij epilogue -----------------
    const int lane = t & 63;
    const int wv   = t >> 6;
    const int quad = lane >> 4;
    const int lm   = lane & 15;

    // Hoist all 12 B-frags (6 n-tiles x 2 k-steps): B[k=kk*32+quad*8+j][n=n0+lm]
    half8_t bf[12];
    #pragma unroll
    for (int nt = 0; nt < 6; ++nt) {
        #pragma unroll
        for (int kk = 0; kk < 2; ++kk)
            bf[nt * 2 + kk] =
                *(const half8_t*)&WbT[(nt * 16 + lm) * SH + kk * 32 + quad * 8];
    }

    for (int mt = wv; mt < MT; mt += 4) {
        const int m0 = mt * 16;
        // A[m=m0+lm][k=kk*32+quad*8+j]
        half8_t a0 = *(const half8_t*)&histS[(m0 + lm) * SH + quad * 8];
        half8_t a1 = *(const half8_t*)&histS[(m0 + lm) * SH + 32 + quad * 8];
        float s0 = 0.f, s1 = 0.f, s2 = 0.f, s3 = 0.f;
        #pragma unroll
        for (int nt = 0; nt < 6; ++nt) {
            floatx4 acc = {0.f, 0.f, 0.f, 0.f};
            acc = __builtin_amdgcn_mfma_f32_16x16x32_f16(a0, bf[nt * 2],     acc, 0, 0, 0);
            acc = __builtin_amdgcn_mfma_f32_16x16x32_f16(a1, bf[nt * 2 + 1], acc, 0, 0, 0);
            // D element: row m = m0 + quad*4 + r (A dim), col n = nt*16 + lm (B dim)
            float be_n = beS[nt * 16 + lm];
            float w2   = aW2S[nt * 16 + lm];
            s0 += fmaxf(acc[0] + be_n, 0.f) * w2;
            s1 += fmaxf(acc[1] + be_n, 0.f) * w2;
            s2 += fmaxf(acc[2] + be_n, 0.f) * w2;
            s3 += fmaxf(acc[3] + be_n, 0.f) * w2;
        }
        // reduce over the 16 lanes of the quad (they share the same 4 m's)
        #pragma unroll
        for (int off = 1; off < 16; off <<= 1) {
            s0 += __shfl_xor(s0, off);
            s1 += __shfl_xor(s1, off);
            s2 += __shfl_xor(s2, off);
            s3 += __shfl_xor(s3, off);
        }
        if (lm == 0) {
            int mr = m0 + quad * 4;
            aijS[mr + 0] = s0 + ab2S;
            aijS[mr + 1] = s1 + ab2S;
            aijS[mr + 2] = s2 + ab2S;
            aijS[mr + 3] = s3 + ab2S;
        }
    }
    __syncthreads();

    // ---- Phase C: tmp[k] = sum_m aij[m]*H[m][k] -----------------------
    {
        int k = t & 63, g = t >> 6;
        float s = 0.f;
        for (int m = g * 50; m < g * 50 + 50; ++m)
            s += aijS[m] * (float)histS[m * SH + k];
        partS[g * E + k] = s;
    }
    __syncthreads();

    // x = [tmp | target | other]
    if (t < 64)
        xS[t] = partS[t] + partS[64 + t] + partS[128 + t] + partS[192 + t];
    else if (t < 128)
        xS[t] = tgtS[t - 64];
    else
        xS[t] = other[(size_t)b * 128 + (t - 128)];
    __syncthreads();

    // ---- Phase D: MLP head --------------------------------------------
    // L1: 256->128, split c-range across thread halves
    {
        int j = t & 127, ph = t >> 7;
        float s = ph ? 0.f : ob1[j];
        const float* w = oW1 + (size_t)(ph * 128) * F1 + j;
        int c0 = ph * 128;
        for (int c = 0; c < 128; ++c)
            s += xS[c0 + c] * w[(size_t)c * F1];
        h1p[ph * 128 + j] = s;
    }
    __syncthreads();
    if (t < F1) h1S[t] = fmaxf(h1p[t] + h1p[128 + t], 0.f);
    __syncthreads();

    // L2: 128->85
    {
        int o = t & 127, ph = t >> 7;
        if (o < F2) {
            float s = ph ? 0.f : ob2[o];
            int c0 = ph * 64;
            for (int c = c0; c < c0 + 64; ++c)
                s += h1S[c] * oW2[(size_t)c * F2 + o];
            h2p[ph * 128 + o] = s;
        }
    }
    __syncthreads();
    if (t < F2) h2S[t] = fmaxf(h2p[t] + h2p[128 + t], 0.f);
    __syncthreads();

    // L3: 85->64
    if (t < F3) {
        float s = ob3[t];
        for (int c = 0; c < F2; ++c)
            s += h2S[c] * oW3[(size_t)c * F3 + t];
        h3S[t] = fmaxf(s, 0.f);
    }
    __syncthreads();

    // Final: 64->1, sigmoid
    if (t < 64) {
        float v = h3S[t] * fW[t];
        v += __shfl_xor(v, 1);  v += __shfl_xor(v, 2);  v += __shfl_xor(v, 4);
        v += __shfl_xor(v, 8);  v += __shfl_xor(v, 16); v += __shfl_xor(v, 32);
        if (t == 0) out[b] = 1.f / (1.f + __expf(-(v + fb[0])));
    }
}

extern "C" void kernel_launch(void* const* d_in, const int* in_sizes, int n_in,
                              void* d_out, int out_size, void* d_ws, size_t ws_size,
                              hipStream_t stream) {
    const float* hist   = (const float*)d_in[0];
    const float* target = (const float*)d_in[1];
    const float* other  = (const float*)d_in[2];
    const float* aW1    = (const float*)d_in[3];
    const float* ab1    = (const float*)d_in[4];
    const float* aW2    = (const float*)d_in[5];
    const float* ab2    = (const float*)d_in[6];
    const float* oW1    = (const float*)d_in[7];
    const float* ob1    = (const float*)d_in[8];
    const float* oW2    = (const float*)d_in[9];
    const float* ob2    = (const float*)d_in[10];
    const float* oW3    = (const float*)d_in[11];
    const float* ob3    = (const float*)d_in[12];
    const float* fW     = (const float*)d_in[13];
    const float* fb     = (const float*)d_in[14];
    float* out = (float*)d_out;

    din_kernel<<<BATCH, 256, 0, stream>>>(hist, target, other,
                                          aW1, ab1, aW2, ab2,
                                          oW1, ob1, oW2, ob2, oW3, ob3,
                                          fW, fb, out);
}

// Round 3
// 746.261 us; speedup vs baseline: 2.4184x; 1.1044x over previous
//
#include <hip/hip_runtime.h>
#include <math.h>

#define BATCH 8192
#define M 200
#define E 64
#define H1 96    // ADIM/2
#define F1 128   // FEA/2
#define F2 85    // FEA/3
#define F3 64    // FEA/4
#define SH 72    // WbT row stride in halfs
#define MT 13    // ceil(200/16) m-tiles

typedef _Float16 half8_t __attribute__((ext_vector_type(8)));
typedef float floatx4 __attribute__((ext_vector_type(4)));

// One block per batch row b. No hist LDS staging:
//  A) fold WbT = (aW1a + diag(tgt)aW1b)^T (fp16), be = ab1 + tgt@aW1c
//  B) per wave: hoist 12 B-frags; loop over m-tiles: A-frags direct from
//     global (float4, coalesced), MFMA -> relu(+be)@aW2 -> aij (in-wave
//     butterfly + broadcast), accumulate tmp[k] contributions in registers
//  C) in-quad butterfly of tk, per-wave partials to LDS, reduce
//  D) fused MLP head 256->128->85->64->sigmoid
__global__ __launch_bounds__(256, 4) void din_kernel(
    const float* __restrict__ hist, const float* __restrict__ target,
    const float* __restrict__ other,
    const float* __restrict__ aW1, const float* __restrict__ ab1,
    const float* __restrict__ aW2, const float* __restrict__ ab2,
    const float* __restrict__ oW1, const float* __restrict__ ob1,
    const float* __restrict__ oW2, const float* __restrict__ ob2,
    const float* __restrict__ oW3, const float* __restrict__ ob3,
    const float* __restrict__ fW,  const float* __restrict__ fb,
    float* __restrict__ out)
{
    __shared__ _Float16 WbT[H1 * SH];      // 13824 B, row j: k-contiguous
    __shared__ float tgtS[E];
    __shared__ float beS[H1];
    __shared__ float aW2S[H1];
    __shared__ float partS[4 * E];
    __shared__ float xS[256];
    __shared__ float h1p[256];
    __shared__ float h1S[F1];
    __shared__ float h2p[256];
    __shared__ float h2S[F2];
    __shared__ float h3S[F3];
    __shared__ float ab2S;

    const int t = threadIdx.x;
    const int b = blockIdx.x;

    if (t < E) tgtS[t] = target[(size_t)b * E + t];
    if (t == 0) ab2S = ab2[0];
    __syncthreads();

    // ---- Phase A: weight folds ----------------------------------------
    for (int idx = t; idx < E * H1; idx += 256) {
        int k = idx / H1, j = idx - k * H1;
        float w = aW1[idx] + tgtS[k] * aW1[E * H1 + idx];
        WbT[j * SH + k] = (_Float16)w;
    }
    if (t < H1) {
        float s = ab1[t];
        for (int k = 0; k < E; ++k)
            s += tgtS[k] * aW1[(2 * E + k) * H1 + t];
        beS[t] = s;
        aW2S[t] = aW2[t];
    }
    __syncthreads();

    // ---- Phase B: MFMA + fused aij + in-register tmp accumulation -----
    const int lane = t & 63;
    const int wv   = t >> 6;
    const int quad = lane >> 4;
    const int lm   = lane & 15;

    // B[k=kk*32+quad*8+j][n=nt*16+lm]
    half8_t bf[12];
    #pragma unroll
    for (int nt = 0; nt < 6; ++nt) {
        #pragma unroll
        for (int kk = 0; kk < 2; ++kk)
            bf[nt * 2 + kk] =
                *(const half8_t*)&WbT[(nt * 16 + lm) * SH + kk * 32 + quad * 8];
    }

    float tk0[8], tk1[8];
    #pragma unroll
    for (int j = 0; j < 8; ++j) { tk0[j] = 0.f; tk1[j] = 0.f; }

    const int qs16 = (lm >> 2) << 4;
    const int rsel = lm & 3;

    for (int mt = wv; mt < MT; mt += 4) {
        const int m0 = mt * 16;
        const int row = m0 + lm;
        const int rowc = row < M ? row : (M - 1);
        const float4* p = (const float4*)(hist + ((size_t)b * M + rowc) * E + quad * 8);
        float4 f0 = p[0], g0 = p[1];    // k = quad*8 .. +7
        float4 f1 = p[8], g1 = p[9];    // k = 32+quad*8 .. +7
        half8_t a0 = { (_Float16)f0.x, (_Float16)f0.y, (_Float16)f0.z, (_Float16)f0.w,
                       (_Float16)g0.x, (_Float16)g0.y, (_Float16)g0.z, (_Float16)g0.w };
        half8_t a1 = { (_Float16)f1.x, (_Float16)f1.y, (_Float16)f1.z, (_Float16)f1.w,
                       (_Float16)g1.x, (_Float16)g1.y, (_Float16)g1.z, (_Float16)g1.w };

        float s0 = 0.f, s1 = 0.f, s2 = 0.f, s3 = 0.f;
        #pragma unroll
        for (int nt = 0; nt < 6; ++nt) {
            floatx4 acc = {0.f, 0.f, 0.f, 0.f};
            acc = __builtin_amdgcn_mfma_f32_16x16x32_f16(a0, bf[nt * 2],     acc, 0, 0, 0);
            acc = __builtin_amdgcn_mfma_f32_16x16x32_f16(a1, bf[nt * 2 + 1], acc, 0, 0, 0);
            float be_n = beS[nt * 16 + lm];
            float w2   = aW2S[nt * 16 + lm];
            s0 += fmaxf(acc[0] + be_n, 0.f) * w2;
            s1 += fmaxf(acc[1] + be_n, 0.f) * w2;
            s2 += fmaxf(acc[2] + be_n, 0.f) * w2;
            s3 += fmaxf(acc[3] + be_n, 0.f) * w2;
        }
        // sum over the 16 cols handled by this quad (rows m0+quad*4+r)
        #pragma unroll
        for (int off = 1; off < 16; off <<= 1) {
            s0 += __shfl_xor(s0, off);
            s1 += __shfl_xor(s1, off);
            s2 += __shfl_xor(s2, off);
            s3 += __shfl_xor(s3, off);
        }
        // broadcast: lane needs aij[row=m0+lm] = quad(lm>>2)'s s_{lm&3}
        float v0 = __shfl(s0, qs16), v1 = __shfl(s1, qs16);
        float v2 = __shfl(s2, qs16), v3 = __shfl(s3, qs16);
        float aij = (rsel == 0) ? v0 : (rsel == 1) ? v1 : (rsel == 2) ? v2 : v3;
        aij += ab2S;
        aij = (row < M) ? aij : 0.f;

        // tmp[k] += aij * H[row][k]  (k = quad*8+j and 32+quad*8+j)
        tk0[0] += f0.x * aij; tk0[1] += f0.y * aij;
        tk0[2] += f0.z * aij; tk0[3] += f0.w * aij;
        tk0[4] += g0.x * aij; tk0[5] += g0.y * aij;
        tk0[6] += g0.z * aij; tk0[7] += g0.w * aij;
        tk1[0] += f1.x * aij; tk1[1] += f1.y * aij;
        tk1[2] += f1.z * aij; tk1[3] += f1.w * aij;
        tk1[4] += g1.x * aij; tk1[5] += g1.y * aij;
        tk1[6] += g1.z * aij; tk1[7] += g1.w * aij;
    }

    // ---- Phase C: reduce tk over quad lanes, write per-wave partials --
    #pragma unroll
    for (int j = 0; j < 8; ++j) {
        #pragma unroll
        for (int off = 1; off < 16; off <<= 1) {
            tk0[j] += __shfl_xor(tk0[j], off);
            tk1[j] += __shfl_xor(tk1[j], off);
        }
    }
    if (lm == 0) {
        #pragma unroll
        for (int j = 0; j < 8; ++j) {
            partS[wv * E + quad * 8 + j]      = tk0[j];
            partS[wv * E + 32 + quad * 8 + j] = tk1[j];
        }
    }
    __syncthreads();

    // x = [tmp | target | other]
    if (t < 64)
        xS[t] = partS[t] + partS[64 + t] + partS[128 + t] + partS[192 + t];
    else if (t < 128)
        xS[t] = tgtS[t - 64];
    else
        xS[t] = other[(size_t)b * 128 + (t - 128)];
    __syncthreads();

    // ---- Phase D: MLP head --------------------------------------------
    {
        int j = t & 127, ph = t >> 7;
        float s = ph ? 0.f : ob1[j];
        const float* w = oW1 + (size_t)(ph * 128) * F1 + j;
        int c0 = ph * 128;
        for (int c = 0; c < 128; ++c)
            s += xS[c0 + c] * w[(size_t)c * F1];
        h1p[ph * 128 + j] = s;
    }
    __syncthreads();
    if (t < F1) h1S[t] = fmaxf(h1p[t] + h1p[128 + t], 0.f);
    __syncthreads();

    {
        int o = t & 127, ph = t >> 7;
        if (o < F2) {
            float s = ph ? 0.f : ob2[o];
            int c0 = ph * 64;
            for (int c = c0; c < c0 + 64; ++c)
                s += h1S[c] * oW2[(size_t)c * F2 + o];
            h2p[ph * 128 + o] = s;
        }
    }
    __syncthreads();
    if (t < F2) h2S[t] = fmaxf(h2p[t] + h2p[128 + t], 0.f);
    __syncthreads();

    if (t < F3) {
        float s = ob3[t];
        for (int c = 0; c < F2; ++c)
            s += h2S[c] * oW3[(size_t)c * F3 + t];
        h3S[t] = fmaxf(s, 0.f);
    }
    __syncthreads();

    if (t < 64) {
        float v = h3S[t] * fW[t];
        v += __shfl_xor(v, 1);  v += __shfl_xor(v, 2);  v += __shfl_xor(v, 4);
        v += __shfl_xor(v, 8);  v += __shfl_xor(v, 16); v += __shfl_xor(v, 32);
        if (t == 0) out[b] = 1.f / (1.f + __expf(-(v + fb[0])));
    }
}

extern "C" void kernel_launch(void* const* d_in, const int* in_sizes, int n_in,
                              void* d_out, int out_size, void* d_ws, size_t ws_size,
                              hipStream_t stream) {
    const float* hist   = (const float*)d_in[0];
    const float* target = (const float*)d_in[1];
    const float* other  = (const float*)d_in[2];
    const float* aW1    = (const float*)d_in[3];
    const float* ab1    = (const float*)d_in[4];
    const float* aW2    = (const float*)d_in[5];
    const float* ab2    = (const float*)d_in[6];
    const float* oW1    = (const float*)d_in[7];
    const float* ob1    = (const float*)d_in[8];
    const float* oW2    = (const float*)d_in[9];
    const float* ob2    = (const float*)d_in[10];
    const float* oW3    = (const float*)d_in[11];
    const float* ob3    = (const float*)d_in[12];
    const float* fW     = (const float*)d_in[13];
    const float* fb     = (const float*)d_in[14];
    float* out = (float*)d_out;

    din_kernel<<<BATCH, 256, 0, stream>>>(hist, target, other,
                                          aW1, ab1, aW2, ab2,
                                          oW1, ob1, oW2, ob2, oW3, ob3,
                                          fW, fb, out);
}